// Round 8
// baseline (243.012 us; speedup 1.0000x reference)
//
#include <hip/hip_runtime.h>
#include <hip/hip_bf16.h>
#include <math.h>

#define NSENT 65536
#define NBAGS 4096
#define DIM 768
#define D4 192            // DIM/4 (float4 per row)
#define DU4 192           // ushort4 per bf16 row (768/4)
#define FLATC 53
#define CPAD 64           // padded class count for probs MFMA
#define GCLS 96           // padded global class count (95 real + 1 zero row)
#define KTOT 2304         // 3*DIM
#define K4 576            // KTOT/4
#define CHUNK 512
#define RB 64             // rows per logit_gemm3 block
#define KC 128            // k-chunk (bf16) staged in LDS
#define KSLOT 16          // 16B slots per row (128 bf16)
#define LTS 100           // Ltile row stride (floats), avoids bank conflicts

typedef short bf16x8 __attribute__((ext_vector_type(8)));
typedef float f32x4 __attribute__((ext_vector_type(4)));

__device__ __forceinline__ float wsum(float v) {
#pragma unroll
  for (int o = 32; o; o >>= 1) v += __shfl_xor(v, o);
  return v;
}
__device__ __forceinline__ float wmax(float v) {
#pragma unroll
  for (int o = 32; o; o >>= 1) v = fmaxf(v, __shfl_xor(v, o));
  return v;
}
__device__ __forceinline__ unsigned short f2bf(float f) {
  union { __hip_bfloat16 b; unsigned short s; } cv;
  cv.b = __float2bfloat16(f);
  return cv.s;
}
__device__ __forceinline__ float bf2f(unsigned short s) {
  return __uint_as_float(((unsigned int)s) << 16);
}
__device__ __forceinline__ bf16x8 cvt8(float4 lo, float4 hi) {
  union { bf16x8 v; unsigned short s[8]; } u;
  u.s[0] = f2bf(lo.x); u.s[1] = f2bf(lo.y); u.s[2] = f2bf(lo.z); u.s[3] = f2bf(lo.w);
  u.s[4] = f2bf(hi.x); u.s[5] = f2bf(hi.y); u.s[6] = f2bf(hi.z); u.s[7] = f2bf(hi.w);
  return u.v;
}

// ---- K1: aw -> bf16 [96][768] (row 95 zero); rw -> bf16 [64][2304] ----
__global__ __launch_bounds__(256) void cvt_weights(
    const float* __restrict__ aw, const float* __restrict__ rw,
    unsigned short* __restrict__ aw16, unsigned short* __restrict__ rw16) {
  const int idx = blockIdx.x * 256 + threadIdx.x;
  const int NAW = GCLS * DIM;
  if (idx < NAW) {
    const int row = idx / DIM;
    aw16[idx] = f2bf(row < 95 ? aw[idx] : 0.f);
  } else if (idx < NAW + CPAD * KTOT) {
    const int j = idx - NAW;
    const int row = j / KTOT;
    rw16[j] = f2bf(row < FLATC ? rw[j] : 0.f);
  }
}

// ---- K2: logits via LDS-staged bf16 MFMA; fused x16 write + lg gather ----
// Block = 64 rows x 96 classes, 4 waves (wave = one 16-row tile).
// 1024 blocks -> 4 blocks/CU, 16 waves/CU. Staging also emits x16 (bf16 x).
// Epilogue: 64x96 logit tile -> LDS -> gather 3 logits/sentence -> lg.
__global__ __launch_bounds__(256) void logit_gemm3(
    const float* __restrict__ x, const int* __restrict__ q,
    const unsigned short* __restrict__ aw16,
    unsigned short* __restrict__ x16, float* __restrict__ lgout) {
  __shared__ unsigned char smem[RB * LTS * 4];  // 25.6 KB, aliased
  unsigned short* As = (unsigned short*)smem;   // staging: RB*KC bf16 = 16 KB
  float* Lt = (float*)smem;                     // epilogue: RB x LTS f32

  const int tid = threadIdx.x;
  const int wv = tid >> 6;
  const int lane = tid & 63;
  const int r = lane & 15;
  const int kg = lane >> 4;
  const int m0 = blockIdx.x * RB;

  f32x4 acc[6];
#pragma unroll
  for (int ct = 0; ct < 6; ct++) acc[ct] = (f32x4){0.f, 0.f, 0.f, 0.f};

  const int arow = wv * 16 + r;

  for (int kc = 0; kc < DIM; kc += KC) {
    __syncthreads();  // protect As from previous phase's readers
    // stage: flat f = tid + 256*it; row = f>>4, slot = f&15 (slot = 8 bf16)
#pragma unroll
    for (int it = 0; it < (RB * KSLOT) / 256; ++it) {  // 4 iterations
      const int f = tid + it * 256;
      const int row = f >> 4;
      const int slot = f & 15;
      const float4* src =
          (const float4*)(x + (size_t)(m0 + row) * DIM + kc + slot * 8);
      const bf16x8 v = cvt8(src[0], src[1]);
      *(bf16x8*)(As + (((row << 4) | (slot ^ (row & 7))) << 3)) = v;
      // fused bf16-x emission (coalesced 16B stores)
      *(bf16x8*)(x16 + (size_t)(m0 + row) * DIM + kc + slot * 8) = v;
    }
    __syncthreads();

    const unsigned short* bp = aw16 + (size_t)r * DIM + kc + kg * 8;
#pragma unroll
    for (int ks = 0; ks < KC; ks += 32) {
      const int sb = (ks >> 3) + kg;
      const bf16x8 a =
          *(const bf16x8*)(As + (((arow << 4) | (sb ^ (arow & 7))) << 3));
#pragma unroll
      for (int ct = 0; ct < 6; ct++) {
        const bf16x8 b = *(const bf16x8*)(bp + (size_t)ct * 16 * DIM + ks);
        acc[ct] = __builtin_amdgcn_mfma_f32_16x16x32_bf16(a, b, acc[ct], 0, 0, 0);
      }
    }
  }

  // epilogue: D tile -> LDS (row = wv*16 + kg*4 + reg, col = ct*16 + r)
  __syncthreads();
#pragma unroll
  for (int ct = 0; ct < 6; ct++)
#pragma unroll
    for (int reg = 0; reg < 4; reg++)
      Lt[(wv * 16 + kg * 4 + reg) * LTS + ct * 16 + r] = acc[ct][reg];
  __syncthreads();

  // gather: thread t < 64 emits the 3 selected logits of sentence m0+t
  if (tid < RB) {
    const int n = m0 + tid;
#pragma unroll
    for (int l = 0; l < 3; l++)
      lgout[3 * n + l] = Lt[tid * LTS + q[3 * n + l]];
  }
}

// ---- K3: per-bag softmax + weighted sum over bf16 x16 ----
__global__ __launch_bounds__(192) void bag_sum(
    const unsigned short* __restrict__ x16, const float* __restrict__ lgin,
    const int* __restrict__ scope, float* __restrict__ out,
    unsigned short* __restrict__ lt16) {
  const int b = blockIdx.x;
  const int s0 = scope[b];
  const int s1 = scope[b + 1];
  const int len = s1 - s0;
  const int tid = threadIdx.x;
  const int wave = tid >> 6;
  const int lane = tid & 63;

  __shared__ float lg[CHUNK][3];
  __shared__ float sm[3], se[3];

  float m[3] = {-INFINITY, -INFINITY, -INFINITY};
  float dsum[3] = {0.f, 0.f, 0.f};
  float4 acc[3];
#pragma unroll
  for (int l = 0; l < 3; l++) acc[l] = make_float4(0.f, 0.f, 0.f, 0.f);

  const ushort4* __restrict__ X16 = (const ushort4*)x16;  // 192 per row

  for (int cs = 0; cs < len; cs += CHUNK) {
    const int clen = min(CHUNK, len - cs);

    for (int idx = tid; idx < 3 * clen; idx += 192)
      ((float*)lg)[idx] = lgin[(size_t)(s0 + cs) * 3 + idx];
    __syncthreads();

    {
      const int l = wave;
      float cm = -INFINITY;
      for (int i = lane; i < clen; i += 64) cm = fmaxf(cm, lg[i][l]);
      cm = wmax(cm);
      const float mn = fmaxf(m[l], cm);
      float es = 0.f;
      for (int i = lane; i < clen; i += 64) {
        const float e = __expf(lg[i][l] - mn);
        es += e;
        lg[i][l] = e;
      }
      es = wsum(es);
      if (lane == 0) { sm[l] = mn; se[l] = es; }
    }
    __syncthreads();

#pragma unroll
    for (int l = 0; l < 3; l++) {
      const float mn = sm[l];
      const float sc = __expf(m[l] - mn);
      m[l] = mn;
      dsum[l] = dsum[l] * sc + se[l];
      acc[l].x *= sc; acc[l].y *= sc; acc[l].z *= sc; acc[l].w *= sc;
    }

    {
      int i = 0;
      for (; i + 4 <= clen; i += 4) {
        ushort4 xu[4];
        float w0[4], w1[4], w2[4];
#pragma unroll
        for (int j = 0; j < 4; j++) {
          xu[j] = X16[(size_t)(s0 + cs + i + j) * DU4 + tid];
          w0[j] = lg[i + j][0];
          w1[j] = lg[i + j][1];
          w2[j] = lg[i + j][2];
        }
#pragma unroll
        for (int j = 0; j < 4; j++) {
          const float vx = bf2f(xu[j].x), vy = bf2f(xu[j].y);
          const float vz = bf2f(xu[j].z), vw = bf2f(xu[j].w);
          acc[0].x += w0[j] * vx; acc[0].y += w0[j] * vy;
          acc[0].z += w0[j] * vz; acc[0].w += w0[j] * vw;
          acc[1].x += w1[j] * vx; acc[1].y += w1[j] * vy;
          acc[1].z += w1[j] * vz; acc[1].w += w1[j] * vw;
          acc[2].x += w2[j] * vx; acc[2].y += w2[j] * vy;
          acc[2].z += w2[j] * vz; acc[2].w += w2[j] * vw;
        }
      }
      for (; i < clen; i++) {
        const float a0 = lg[i][0], a1 = lg[i][1], a2 = lg[i][2];
        const ushort4 xu = X16[(size_t)(s0 + cs + i) * DU4 + tid];
        const float vx = bf2f(xu.x), vy = bf2f(xu.y);
        const float vz = bf2f(xu.z), vw = bf2f(xu.w);
        acc[0].x += a0 * vx; acc[0].y += a0 * vy; acc[0].z += a0 * vz; acc[0].w += a0 * vw;
        acc[1].x += a1 * vx; acc[1].y += a1 * vy; acc[1].z += a1 * vz; acc[1].w += a1 * vw;
        acc[2].x += a2 * vx; acc[2].y += a2 * vy; acc[2].z += a2 * vz; acc[2].w += a2 * vw;
      }
    }
    __syncthreads();
  }

  float4* o0 = (float4*)out;                              // stack [3][B][D]
  float4* o1 = (float4*)(out + (size_t)3 * NBAGS * DIM);  // lt [B][3*D]
  ushort4* l16 = (ushort4*)(lt16 + (size_t)b * KTOT);
#pragma unroll
  for (int l = 0; l < 3; l++) {
    const float inv = (dsum[l] > 0.f) ? (1.f / dsum[l]) : 0.f;
    float4 v = acc[l];
    v.x *= inv; v.y *= inv; v.z *= inv; v.w *= inv;
    o0[((size_t)l * NBAGS + b) * D4 + tid] = v;
    o1[(size_t)b * K4 + l * D4 + tid] = v;
    ushort4 h;
    h.x = f2bf(v.x); h.y = f2bf(v.y); h.z = f2bf(v.z); h.w = f2bf(v.w);
    l16[l * D4 + tid] = h;
  }
}

// ---- K4: probs = lt @ rw^T + bias via bf16 MFMA (64 bags x 64 classes) ----
__global__ __launch_bounds__(256) void probs_mfma(
    const unsigned short* __restrict__ lt16,
    const unsigned short* __restrict__ rw16,
    const float* __restrict__ bias, float* __restrict__ outp) {
  const int wv = threadIdx.x >> 6;
  const int lane = threadIdx.x & 63;
  const int r = lane & 15;
  const int kg = lane >> 4;
  const int bagbase = blockIdx.x * 64 + wv * 16;

  f32x4 acc[4];
#pragma unroll
  for (int ct = 0; ct < 4; ct++) acc[ct] = (f32x4){0.f, 0.f, 0.f, 0.f};

  const unsigned short* ap = lt16 + (size_t)(bagbase + r) * KTOT + kg * 8;
  const unsigned short* bp[4];
#pragma unroll
  for (int ct = 0; ct < 4; ct++)
    bp[ct] = rw16 + (size_t)(ct * 16 + r) * KTOT + kg * 8;

  for (int k = 0; k < KTOT; k += 32) {
    const bf16x8 a = *(const bf16x8*)(ap + k);
#pragma unroll
    for (int ct = 0; ct < 4; ct++) {
      const bf16x8 bb = *(const bf16x8*)(bp[ct] + k);
      acc[ct] = __builtin_amdgcn_mfma_f32_16x16x32_bf16(a, bb, acc[ct], 0, 0, 0);
    }
  }

  // D mapping (m89-verified): col = lane&15, row = (lane>>4)*4 + reg
#pragma unroll
  for (int ct = 0; ct < 4; ct++) {
    const int col = ct * 16 + r;
    if (col < FLATC) {
      const float bv = bias[col];
#pragma unroll
      for (int reg = 0; reg < 4; reg++) {
        const int bag = bagbase + kg * 4 + reg;
        outp[(size_t)bag * FLATC + col] = acc[ct][reg] + bv;
      }
    }
  }
}

extern "C" void kernel_launch(void* const* d_in, const int* in_sizes, int n_in,
                              void* d_out, int out_size, void* d_ws,
                              size_t ws_size, hipStream_t stream) {
  const float* x = (const float*)d_in[0];
  const int* aq = (const int*)d_in[1];
  const int* scope = (const int*)d_in[2];
  const float* aw = (const float*)d_in[3];
  const float* rw = (const float*)d_in[4];
  const float* bias = (const float*)d_in[5];
  float* out = (float*)d_out;

  unsigned short* lt16 = (unsigned short*)d_ws;        // 4096*2304
  unsigned short* rw16 = lt16 + (size_t)NBAGS * KTOT;  // 64*2304
  unsigned short* aw16 = rw16 + (size_t)CPAD * KTOT;   // 96*768
  unsigned short* x16 = aw16 + (size_t)GCLS * DIM;     // 65536*768
  float* lg = (float*)(x16 + (size_t)NSENT * DIM);     // 65536*3 f32

  const int ncvt = GCLS * DIM + CPAD * KTOT;
  hipLaunchKernelGGL(cvt_weights, dim3((ncvt + 255) / 256), dim3(256), 0,
                     stream, aw, rw, aw16, rw16);
  hipLaunchKernelGGL(logit_gemm3, dim3(NSENT / RB), dim3(256), 0, stream, x,
                     aq, aw16, x16, lg);
  hipLaunchKernelGGL(bag_sum, dim3(NBAGS), dim3(192), 0, stream, x16, lg,
                     scope, out, lt16);

  float* probs = out + (size_t)3 * NBAGS * DIM + (size_t)NBAGS * KTOT;
  hipLaunchKernelGGL(probs_mfma, dim3(NBAGS / 64), dim3(256), 0, stream, lt16,
                     rw16, bias, probs);
}

// Round 9
// 215.666 us; speedup vs baseline: 1.1268x; 1.1268x over previous
//
#include <hip/hip_runtime.h>
#include <hip/hip_bf16.h>
#include <math.h>

#define NSENT 65536
#define NBAGS 4096
#define DIM 768
#define D4 192            // DIM/4 (float4 per row)
#define FLATC 53
#define CPAD 64           // padded class count for probs MFMA
#define GCLS 96           // padded global class count (95 real + 1 zero row)
#define KTOT 2304         // 3*DIM
#define K4 576            // KTOT/4
#define CHUNK 512
#define RB 64             // sentence rows per logit block
#define KCF 64            // f32 k-columns staged per chunk
#define NCHUNK 12         // 768/64
#define LTS 100           // logit tile row stride (floats)

typedef short bf16x8 __attribute__((ext_vector_type(8)));
typedef float f32x4 __attribute__((ext_vector_type(4)));

__device__ __forceinline__ float wsum(float v) {
#pragma unroll
  for (int o = 32; o; o >>= 1) v += __shfl_xor(v, o);
  return v;
}
__device__ __forceinline__ float wmax(float v) {
#pragma unroll
  for (int o = 32; o; o >>= 1) v = fmaxf(v, __shfl_xor(v, o));
  return v;
}
__device__ __forceinline__ unsigned short f2bf(float f) {
  union { __hip_bfloat16 b; unsigned short s; } cv;
  cv.b = __float2bfloat16(f);
  return cv.s;
}
__device__ __forceinline__ bf16x8 cvt8(float4 lo, float4 hi) {
  union { bf16x8 v; unsigned short s[8]; } u;
  u.s[0] = f2bf(lo.x); u.s[1] = f2bf(lo.y); u.s[2] = f2bf(lo.z); u.s[3] = f2bf(lo.w);
  u.s[4] = f2bf(hi.x); u.s[5] = f2bf(hi.y); u.s[6] = f2bf(hi.z); u.s[7] = f2bf(hi.w);
  return u.v;
}
// 4-bit slot swizzle (2 lanes/bank on ds_read, involution)
__device__ __forceinline__ int swz(int row) {
  return ((row & 7) << 1) | ((row >> 3) & 1);
}

// ---- K1: aw -> bf16 [96][768] (row 95 zero); rw -> bf16 [64][2304] ----
__global__ __launch_bounds__(256) void cvt_weights(
    const float* __restrict__ aw, const float* __restrict__ rw,
    unsigned short* __restrict__ aw16, unsigned short* __restrict__ rw16) {
  const int idx = blockIdx.x * 256 + threadIdx.x;
  const int NAW = GCLS * DIM;
  if (idx < NAW) {
    const int row = idx / DIM;
    aw16[idx] = f2bf(row < 95 ? aw[idx] : 0.f);
  } else if (idx < NAW + CPAD * KTOT) {
    const int j = idx - NAW;
    const int row = j / KTOT;
    rw16[j] = f2bf(row < FLATC ? rw[j] : 0.f);
  }
}

// ---- K2: logits via double-buffered global_load_lds MFMA GEMM ----
// Block = 64 rows x 96 classes, 4 waves. x staged f32 into LDS (16B
// direct-to-LDS, source pre-swizzled); f32->bf16 on LDS read. 2-phase
// software pipeline: STAGE(next) issued before COMPUTE(cur), one barrier
// per chunk -> HBM latency hides under compute + co-resident blocks.
__global__ __launch_bounds__(256) void logit_gemm4(
    const float* __restrict__ x, const int* __restrict__ q,
    const unsigned short* __restrict__ aw16, float* __restrict__ lgout) {
  union SmemU {
    struct { float A[RB * KCF]; float B[RB * KCF]; } s;  // 2 x 16 KB
    float Lt[RB * LTS];                                  // 25.6 KB epilogue
  };
  __shared__ SmemU sm;

  const int tid = threadIdx.x;
  const int wv = tid >> 6;
  const int lane = tid & 63;
  const int r = lane & 15;
  const int kg = lane >> 4;
  const int m0 = blockIdx.x * RB;
  const int arow = wv * 16 + r;

  f32x4 acc[6];
#pragma unroll
  for (int ct = 0; ct < 6; ct++) acc[ct] = (f32x4){0.f, 0.f, 0.f, 0.f};

  // stage chunk t into dst (uniform wave base + lane*16B, linear LDS;
  // global source slot pre-swizzled so LDS[row][s] = global slot s^swz(row))
  auto STAGE = [&](float* dst, int t) {
    const int kc = t * KCF;
#pragma unroll
    for (int i = 0; i < 4; i++) {
      const int j = wv * 4 + i;              // 16 issues cover 64 rows
      const int row = j * 4 + (lane >> 4);   // 4 rows per issue
      const int gslot = (lane & 15) ^ swz(row);
      const float* src = x + (size_t)(m0 + row) * DIM + kc + gslot * 4;
      float* ldsbase = dst + j * 256;        // j*1024 bytes, wave-uniform
      __builtin_amdgcn_global_load_lds(
          (const __attribute__((address_space(1))) unsigned int*)src,
          (__attribute__((address_space(3))) unsigned int*)ldsbase, 16, 0, 0);
    }
  };

  auto COMPUTE = [&](const float* buf, int t) {
    const int kc = t * KCF;
#pragma unroll
    for (int ks = 0; ks < 2; ks++) {
      const int g0 = ks * 8 + kg * 2;
      const int s0 = g0 ^ swz(arow);
      const int s1 = (g0 + 1) ^ swz(arow);
      const float4 lo = *(const float4*)&buf[arow * KCF + s0 * 4];
      const float4 hi = *(const float4*)&buf[arow * KCF + s1 * 4];
      const bf16x8 a = cvt8(lo, hi);
      const unsigned short* bp = aw16 + (size_t)r * DIM + kc + ks * 32 + kg * 8;
#pragma unroll
      for (int ct = 0; ct < 6; ct++) {
        const bf16x8 b = *(const bf16x8*)(bp + (size_t)ct * 16 * DIM);
        acc[ct] = __builtin_amdgcn_mfma_f32_16x16x32_bf16(a, b, acc[ct], 0, 0, 0);
      }
    }
  };

  STAGE(sm.s.A, 0);
  __syncthreads();
#pragma unroll 1
  for (int t = 0; t < NCHUNK; t += 2) {
    STAGE(sm.s.B, t + 1);
    COMPUTE(sm.s.A, t);
    __syncthreads();
    if (t + 2 < NCHUNK) STAGE(sm.s.A, t + 2);
    COMPUTE(sm.s.B, t + 1);
    __syncthreads();
  }

  // epilogue: D tile -> LDS (row = wv*16 + kg*4 + reg, col = ct*16 + r)
#pragma unroll
  for (int ct = 0; ct < 6; ct++)
#pragma unroll
    for (int reg = 0; reg < 4; reg++)
      sm.Lt[(wv * 16 + kg * 4 + reg) * LTS + ct * 16 + r] = acc[ct][reg];
  __syncthreads();

  // gather: thread t < 64 emits the 3 selected logits of sentence m0+t
  if (tid < RB) {
    const int n = m0 + tid;
#pragma unroll
    for (int l = 0; l < 3; l++)
      lgout[3 * n + l] = sm.Lt[tid * LTS + q[3 * n + l]];
  }
}

// ---- K3: per-bag softmax + weighted sum (R4 known-good, f32 x) ----
__global__ __launch_bounds__(192) void bag_sum(
    const float* __restrict__ x, const float* __restrict__ lgin,
    const int* __restrict__ scope, float* __restrict__ out,
    unsigned short* __restrict__ lt16) {
  const int b = blockIdx.x;
  const int s0 = scope[b];
  const int s1 = scope[b + 1];
  const int len = s1 - s0;
  const int tid = threadIdx.x;
  const int wave = tid >> 6;
  const int lane = tid & 63;

  __shared__ float lg[CHUNK][3];
  __shared__ float sm[3], se[3];

  float m[3] = {-INFINITY, -INFINITY, -INFINITY};
  float dsum[3] = {0.f, 0.f, 0.f};
  float4 acc[3];
#pragma unroll
  for (int l = 0; l < 3; l++) acc[l] = make_float4(0.f, 0.f, 0.f, 0.f);

  const float4* __restrict__ X4 = (const float4*)x;

  for (int cs = 0; cs < len; cs += CHUNK) {
    const int clen = min(CHUNK, len - cs);

    for (int idx = tid; idx < 3 * clen; idx += 192)
      ((float*)lg)[idx] = lgin[(size_t)(s0 + cs) * 3 + idx];
    __syncthreads();

    {
      const int l = wave;
      float cm = -INFINITY;
      for (int i = lane; i < clen; i += 64) cm = fmaxf(cm, lg[i][l]);
      cm = wmax(cm);
      const float mn = fmaxf(m[l], cm);
      float es = 0.f;
      for (int i = lane; i < clen; i += 64) {
        const float e = __expf(lg[i][l] - mn);
        es += e;
        lg[i][l] = e;
      }
      es = wsum(es);
      if (lane == 0) { sm[l] = mn; se[l] = es; }
    }
    __syncthreads();

#pragma unroll
    for (int l = 0; l < 3; l++) {
      const float mn = sm[l];
      const float sc = __expf(m[l] - mn);
      m[l] = mn;
      dsum[l] = dsum[l] * sc + se[l];
      acc[l].x *= sc; acc[l].y *= sc; acc[l].z *= sc; acc[l].w *= sc;
    }

    {
      int i = 0;
      for (; i + 4 <= clen; i += 4) {
        float4 xv[4];
        float w0[4], w1[4], w2[4];
#pragma unroll
        for (int j = 0; j < 4; j++) {
          xv[j] = X4[(size_t)(s0 + cs + i + j) * D4 + tid];
          w0[j] = lg[i + j][0];
          w1[j] = lg[i + j][1];
          w2[j] = lg[i + j][2];
        }
#pragma unroll
        for (int j = 0; j < 4; j++) {
          acc[0].x += w0[j] * xv[j].x; acc[0].y += w0[j] * xv[j].y;
          acc[0].z += w0[j] * xv[j].z; acc[0].w += w0[j] * xv[j].w;
          acc[1].x += w1[j] * xv[j].x; acc[1].y += w1[j] * xv[j].y;
          acc[1].z += w1[j] * xv[j].z; acc[1].w += w1[j] * xv[j].w;
          acc[2].x += w2[j] * xv[j].x; acc[2].y += w2[j] * xv[j].y;
          acc[2].z += w2[j] * xv[j].z; acc[2].w += w2[j] * xv[j].w;
        }
      }
      for (; i < clen; i++) {
        const float a0 = lg[i][0], a1 = lg[i][1], a2 = lg[i][2];
        const float4 xv = X4[(size_t)(s0 + cs + i) * D4 + tid];
        acc[0].x += a0 * xv.x; acc[0].y += a0 * xv.y; acc[0].z += a0 * xv.z; acc[0].w += a0 * xv.w;
        acc[1].x += a1 * xv.x; acc[1].y += a1 * xv.y; acc[1].z += a1 * xv.z; acc[1].w += a1 * xv.w;
        acc[2].x += a2 * xv.x; acc[2].y += a2 * xv.y; acc[2].z += a2 * xv.z; acc[2].w += a2 * xv.w;
      }
    }
    __syncthreads();
  }

  float4* o0 = (float4*)out;                              // stack [3][B][D]
  float4* o1 = (float4*)(out + (size_t)3 * NBAGS * DIM);  // lt [B][3*D]
  ushort4* l16 = (ushort4*)(lt16 + (size_t)b * KTOT);
#pragma unroll
  for (int l = 0; l < 3; l++) {
    const float inv = (dsum[l] > 0.f) ? (1.f / dsum[l]) : 0.f;
    float4 v = acc[l];
    v.x *= inv; v.y *= inv; v.z *= inv; v.w *= inv;
    o0[((size_t)l * NBAGS + b) * D4 + tid] = v;
    o1[(size_t)b * K4 + l * D4 + tid] = v;
    ushort4 h;
    h.x = f2bf(v.x); h.y = f2bf(v.y); h.z = f2bf(v.z); h.w = f2bf(v.w);
    l16[l * D4 + tid] = h;
  }
}

// ---- K4: probs = lt @ rw^T + bias via bf16 MFMA (64 bags x 64 classes) ----
__global__ __launch_bounds__(256) void probs_mfma(
    const unsigned short* __restrict__ lt16,
    const unsigned short* __restrict__ rw16,
    const float* __restrict__ bias, float* __restrict__ outp) {
  const int wv = threadIdx.x >> 6;
  const int lane = threadIdx.x & 63;
  const int r = lane & 15;
  const int kg = lane >> 4;
  const int bagbase = blockIdx.x * 64 + wv * 16;

  f32x4 acc[4];
#pragma unroll
  for (int ct = 0; ct < 4; ct++) acc[ct] = (f32x4){0.f, 0.f, 0.f, 0.f};

  const unsigned short* ap = lt16 + (size_t)(bagbase + r) * KTOT + kg * 8;
  const unsigned short* bp[4];
#pragma unroll
  for (int ct = 0; ct < 4; ct++)
    bp[ct] = rw16 + (size_t)(ct * 16 + r) * KTOT + kg * 8;

  for (int k = 0; k < KTOT; k += 32) {
    const bf16x8 a = *(const bf16x8*)(ap + k);
#pragma unroll
    for (int ct = 0; ct < 4; ct++) {
      const bf16x8 bb = *(const bf16x8*)(bp[ct] + k);
      acc[ct] = __builtin_amdgcn_mfma_f32_16x16x32_bf16(a, bb, acc[ct], 0, 0, 0);
    }
  }

  // D mapping (m89-verified): col = lane&15, row = (lane>>4)*4 + reg
#pragma unroll
  for (int ct = 0; ct < 4; ct++) {
    const int col = ct * 16 + r;
    if (col < FLATC) {
      const float bv = bias[col];
#pragma unroll
      for (int reg = 0; reg < 4; reg++) {
        const int bag = bagbase + kg * 4 + reg;
        outp[(size_t)bag * FLATC + col] = acc[ct][reg] + bv;
      }
    }
  }
}

extern "C" void kernel_launch(void* const* d_in, const int* in_sizes, int n_in,
                              void* d_out, int out_size, void* d_ws,
                              size_t ws_size, hipStream_t stream) {
  const float* x = (const float*)d_in[0];
  const int* aq = (const int*)d_in[1];
  const int* scope = (const int*)d_in[2];
  const float* aw = (const float*)d_in[3];
  const float* rw = (const float*)d_in[4];
  const float* bias = (const float*)d_in[5];
  float* out = (float*)d_out;

  unsigned short* lt16 = (unsigned short*)d_ws;        // 4096*2304
  unsigned short* rw16 = lt16 + (size_t)NBAGS * KTOT;  // 64*2304
  unsigned short* aw16 = rw16 + (size_t)CPAD * KTOT;   // 96*768
  float* lg = (float*)(aw16 + (size_t)GCLS * DIM);     // 65536*3 f32

  const int ncvt = GCLS * DIM + CPAD * KTOT;
  hipLaunchKernelGGL(cvt_weights, dim3((ncvt + 255) / 256), dim3(256), 0,
                     stream, aw, rw, aw16, rw16);
  hipLaunchKernelGGL(logit_gemm4, dim3(NSENT / RB), dim3(256), 0, stream, x,
                     aq, aw16, lg);
  hipLaunchKernelGGL(bag_sum, dim3(NBAGS), dim3(192), 0, stream, x, lg, scope,
                     out, lt16);

  float* probs = out + (size_t)3 * NBAGS * DIM + (size_t)NBAGS * KTOT;
  hipLaunchKernelGGL(probs_mfma, dim3(NBAGS / 64), dim3(256), 0, stream, lt16,
                     rw16, bias, probs);
}

// Round 10
// 173.883 us; speedup vs baseline: 1.3976x; 1.2403x over previous
//
#include <hip/hip_runtime.h>
#include <hip/hip_bf16.h>
#include <math.h>

#define NSENT 65536
#define NBAGS 4096
#define DIM 768
#define D4 192            // DIM/4 (float4 per row)
#define FLATC 53
#define CPAD 64           // padded class count for probs MFMA
#define GCLS 96           // padded global class count (95 real + 1 zero row)
#define KTOT 2304         // 3*DIM
#define K4 576            // KTOT/4
#define CHUNK 512

typedef short bf16x8 __attribute__((ext_vector_type(8)));
typedef float f32x4 __attribute__((ext_vector_type(4)));

__device__ __forceinline__ float wsum(float v) {
#pragma unroll
  for (int o = 32; o; o >>= 1) v += __shfl_xor(v, o);
  return v;
}
__device__ __forceinline__ float wmax(float v) {
#pragma unroll
  for (int o = 32; o; o >>= 1) v = fmaxf(v, __shfl_xor(v, o));
  return v;
}
__device__ __forceinline__ unsigned short f2bf(float f) {
  union { __hip_bfloat16 b; unsigned short s; } cv;
  cv.b = __float2bfloat16(f);
  return cv.s;
}
__device__ __forceinline__ bf16x8 cvt8(float4 lo, float4 hi) {
  union { bf16x8 v; unsigned short s[8]; } u;
  u.s[0] = f2bf(lo.x); u.s[1] = f2bf(lo.y); u.s[2] = f2bf(lo.z); u.s[3] = f2bf(lo.w);
  u.s[4] = f2bf(hi.x); u.s[5] = f2bf(hi.y); u.s[6] = f2bf(hi.z); u.s[7] = f2bf(hi.w);
  return u.v;
}

// ---- K1: aw -> bf16 [96][768] (row 95 zero); rw -> bf16 [64][2304] ----
__global__ __launch_bounds__(256) void cvt_weights(
    const float* __restrict__ aw, const float* __restrict__ rw,
    unsigned short* __restrict__ aw16, unsigned short* __restrict__ rw16) {
  const int idx = blockIdx.x * 256 + threadIdx.x;
  const int NAW = GCLS * DIM;
  if (idx < NAW) {
    const int row = idx / DIM;
    aw16[idx] = f2bf(row < 95 ? aw[idx] : 0.f);
  } else if (idx < NAW + CPAD * KTOT) {
    const int j = idx - NAW;
    const int row = j / KTOT;
    rw16[j] = f2bf(row < FLATC ? rw[j] : 0.f);
  }
}

// ---- K2: logits via aw-in-LDS, barrier-free per-wave MFMA tiles ----
// 256 blocks x 512 threads (8 waves). aw16 (147 KB) staged ONCE into LDS
// with slot-XOR swizzle (T2). Each wave computes two 16-sentence x 96-class
// tiles: x -> registers (MFMA A-layout, plain loads keep x L3-warm for
// bag_sum), B fragments via ds_read_b128, reduction inside MFMA. The 48
// needed logits per tile are extracted with 24 static shfls (no LDS tile,
// no barriers after the one-time stage).
__global__ __launch_bounds__(512) void logit_mfma(
    const float* __restrict__ x, const int* __restrict__ q,
    const unsigned short* __restrict__ aw16, float* __restrict__ lgout) {
  __shared__ unsigned short awl[GCLS * DIM];  // 147456 B (gfx950: 160K max)
  const int tid = threadIdx.x;
  const int wv = tid >> 6;
  const int lane = tid & 63;
  const int r = lane & 15;
  const int kg = lane >> 4;

  // one-time stage: aw16 -> LDS, 16B chunks, slot XOR-swizzled by row&7
  for (int idx = tid; idx < GCLS * (DIM / 8); idx += 512) {
    const int row = idx / (DIM / 8);
    const int ch = idx - row * (DIM / 8);
    const int chs = ch ^ (row & 7);
    *(bf16x8*)(awl + row * DIM + chs * 8) =
        *(const bf16x8*)(aw16 + (size_t)row * DIM + ch * 8);
  }
  __syncthreads();

  const int key = r & 7;
#pragma unroll 1
  for (int t = 0; t < 2; t++) {
    const int s0 = blockIdx.x * 256 + (wv * 2 + t) * 16;

    int qv = 0;
    if (lane < 48) qv = q[s0 * 3 + lane];  // q[s][l] at lane 3s+l

    f32x4 acc[6];
#pragma unroll
    for (int ct = 0; ct < 6; ct++) acc[ct] = (f32x4){0.f, 0.f, 0.f, 0.f};

    // lane's A-row: sentence s0 + r, k-slice at kg*8
    const float* xr = x + (size_t)(s0 + r) * DIM + kg * 8;
#pragma unroll 4
    for (int ks = 0; ks < 24; ks++) {
      const float4 lo = *(const float4*)(xr + ks * 32);
      const float4 hi = *(const float4*)(xr + ks * 32 + 4);
      const bf16x8 a = cvt8(lo, hi);
      const int slot = ks * 4 + kg;
#pragma unroll
      for (int ct = 0; ct < 6; ct++) {
        const bf16x8 b =
            *(const bf16x8*)(awl + (ct * 16 + r) * DIM + (slot ^ key) * 8);
        acc[ct] = __builtin_amdgcn_mfma_f32_16x16x32_bf16(a, b, acc[ct], 0, 0, 0);
      }
    }

    // epilogue: lane i<48 wants D[s=i/3][c=qv]; D[s][c] lives at
    // lane ((s>>2)<<4)|(c&15), acc[c>>4][s&3]  (m89-verified mapping)
    const int s = lane / 3;
    const int src = ((s >> 2) << 4) | (qv & 15);
    const int ctw = qv >> 4;
    const int regw = s & 3;
    float out = 0.f;
#pragma unroll
    for (int ct = 0; ct < 6; ct++)
#pragma unroll
      for (int reg = 0; reg < 4; reg++) {
        const float v = __shfl(acc[ct][reg], src);
        if (ct == ctw && reg == regw) out = v;
      }
    if (lane < 48) lgout[s0 * 3 + lane] = out;
  }
}

// ---- K3: per-bag softmax + weighted sum (R4 known-good, f32 x) ----
__global__ __launch_bounds__(192) void bag_sum(
    const float* __restrict__ x, const float* __restrict__ lgin,
    const int* __restrict__ scope, float* __restrict__ out,
    unsigned short* __restrict__ lt16) {
  const int b = blockIdx.x;
  const int s0 = scope[b];
  const int s1 = scope[b + 1];
  const int len = s1 - s0;
  const int tid = threadIdx.x;
  const int wave = tid >> 6;
  const int lane = tid & 63;

  __shared__ float lg[CHUNK][3];
  __shared__ float sm[3], se[3];

  float m[3] = {-INFINITY, -INFINITY, -INFINITY};
  float dsum[3] = {0.f, 0.f, 0.f};
  float4 acc[3];
#pragma unroll
  for (int l = 0; l < 3; l++) acc[l] = make_float4(0.f, 0.f, 0.f, 0.f);

  const float4* __restrict__ X4 = (const float4*)x;

  for (int cs = 0; cs < len; cs += CHUNK) {
    const int clen = min(CHUNK, len - cs);

    for (int idx = tid; idx < 3 * clen; idx += 192)
      ((float*)lg)[idx] = lgin[(size_t)(s0 + cs) * 3 + idx];
    __syncthreads();

    {
      const int l = wave;
      float cm = -INFINITY;
      for (int i = lane; i < clen; i += 64) cm = fmaxf(cm, lg[i][l]);
      cm = wmax(cm);
      const float mn = fmaxf(m[l], cm);
      float es = 0.f;
      for (int i = lane; i < clen; i += 64) {
        const float e = __expf(lg[i][l] - mn);
        es += e;
        lg[i][l] = e;
      }
      es = wsum(es);
      if (lane == 0) { sm[l] = mn; se[l] = es; }
    }
    __syncthreads();

#pragma unroll
    for (int l = 0; l < 3; l++) {
      const float mn = sm[l];
      const float sc = __expf(m[l] - mn);
      m[l] = mn;
      dsum[l] = dsum[l] * sc + se[l];
      acc[l].x *= sc; acc[l].y *= sc; acc[l].z *= sc; acc[l].w *= sc;
    }

    {
      int i = 0;
      for (; i + 4 <= clen; i += 4) {
        float4 xv[4];
        float w0[4], w1[4], w2[4];
#pragma unroll
        for (int j = 0; j < 4; j++) {
          xv[j] = X4[(size_t)(s0 + cs + i + j) * D4 + tid];
          w0[j] = lg[i + j][0];
          w1[j] = lg[i + j][1];
          w2[j] = lg[i + j][2];
        }
#pragma unroll
        for (int j = 0; j < 4; j++) {
          acc[0].x += w0[j] * xv[j].x; acc[0].y += w0[j] * xv[j].y;
          acc[0].z += w0[j] * xv[j].z; acc[0].w += w0[j] * xv[j].w;
          acc[1].x += w1[j] * xv[j].x; acc[1].y += w1[j] * xv[j].y;
          acc[1].z += w1[j] * xv[j].z; acc[1].w += w1[j] * xv[j].w;
          acc[2].x += w2[j] * xv[j].x; acc[2].y += w2[j] * xv[j].y;
          acc[2].z += w2[j] * xv[j].z; acc[2].w += w2[j] * xv[j].w;
        }
      }
      for (; i < clen; i++) {
        const float a0 = lg[i][0], a1 = lg[i][1], a2 = lg[i][2];
        const float4 xv = X4[(size_t)(s0 + cs + i) * D4 + tid];
        acc[0].x += a0 * xv.x; acc[0].y += a0 * xv.y; acc[0].z += a0 * xv.z; acc[0].w += a0 * xv.w;
        acc[1].x += a1 * xv.x; acc[1].y += a1 * xv.y; acc[1].z += a1 * xv.z; acc[1].w += a1 * xv.w;
        acc[2].x += a2 * xv.x; acc[2].y += a2 * xv.y; acc[2].z += a2 * xv.z; acc[2].w += a2 * xv.w;
      }
    }
    __syncthreads();
  }

  float4* o0 = (float4*)out;                              // stack [3][B][D]
  float4* o1 = (float4*)(out + (size_t)3 * NBAGS * DIM);  // lt [B][3*D]
  ushort4* l16 = (ushort4*)(lt16 + (size_t)b * KTOT);
#pragma unroll
  for (int l = 0; l < 3; l++) {
    const float inv = (dsum[l] > 0.f) ? (1.f / dsum[l]) : 0.f;
    float4 v = acc[l];
    v.x *= inv; v.y *= inv; v.z *= inv; v.w *= inv;
    o0[((size_t)l * NBAGS + b) * D4 + tid] = v;
    o1[(size_t)b * K4 + l * D4 + tid] = v;
    ushort4 h;
    h.x = f2bf(v.x); h.y = f2bf(v.y); h.z = f2bf(v.z); h.w = f2bf(v.w);
    l16[l * D4 + tid] = h;
  }
}

// ---- K4: probs = lt @ rw^T + bias via bf16 MFMA (64 bags x 64 classes) ----
__global__ __launch_bounds__(256) void probs_mfma(
    const unsigned short* __restrict__ lt16,
    const unsigned short* __restrict__ rw16,
    const float* __restrict__ bias, float* __restrict__ outp) {
  const int wv = threadIdx.x >> 6;
  const int lane = threadIdx.x & 63;
  const int r = lane & 15;
  const int kg = lane >> 4;
  const int bagbase = blockIdx.x * 64 + wv * 16;

  f32x4 acc[4];
#pragma unroll
  for (int ct = 0; ct < 4; ct++) acc[ct] = (f32x4){0.f, 0.f, 0.f, 0.f};

  const unsigned short* ap = lt16 + (size_t)(bagbase + r) * KTOT + kg * 8;
  const unsigned short* bp[4];
#pragma unroll
  for (int ct = 0; ct < 4; ct++)
    bp[ct] = rw16 + (size_t)(ct * 16 + r) * KTOT + kg * 8;

  for (int k = 0; k < KTOT; k += 32) {
    const bf16x8 a = *(const bf16x8*)(ap + k);
#pragma unroll
    for (int ct = 0; ct < 4; ct++) {
      const bf16x8 bb = *(const bf16x8*)(bp[ct] + k);
      acc[ct] = __builtin_amdgcn_mfma_f32_16x16x32_bf16(a, bb, acc[ct], 0, 0, 0);
    }
  }

  // D mapping (m89-verified): col = lane&15, row = (lane>>4)*4 + reg
#pragma unroll
  for (int ct = 0; ct < 4; ct++) {
    const int col = ct * 16 + r;
    if (col < FLATC) {
      const float bv = bias[col];
#pragma unroll
      for (int reg = 0; reg < 4; reg++) {
        const int bag = bagbase + kg * 4 + reg;
        outp[(size_t)bag * FLATC + col] = acc[ct][reg] + bv;
      }
    }
  }
}

extern "C" void kernel_launch(void* const* d_in, const int* in_sizes, int n_in,
                              void* d_out, int out_size, void* d_ws,
                              size_t ws_size, hipStream_t stream) {
  const float* x = (const float*)d_in[0];
  const int* aq = (const int*)d_in[1];
  const int* scope = (const int*)d_in[2];
  const float* aw = (const float*)d_in[3];
  const float* rw = (const float*)d_in[4];
  const float* bias = (const float*)d_in[5];
  float* out = (float*)d_out;

  unsigned short* lt16 = (unsigned short*)d_ws;        // 4096*2304
  unsigned short* rw16 = lt16 + (size_t)NBAGS * KTOT;  // 64*2304
  unsigned short* aw16 = rw16 + (size_t)CPAD * KTOT;   // 96*768
  float* lg = (float*)(aw16 + (size_t)GCLS * DIM);     // 65536*3 f32

  const int ncvt = GCLS * DIM + CPAD * KTOT;
  hipLaunchKernelGGL(cvt_weights, dim3((ncvt + 255) / 256), dim3(256), 0,
                     stream, aw, rw, aw16, rw16);
  hipLaunchKernelGGL(logit_mfma, dim3(NSENT / 256), dim3(512), 0, stream, x,
                     aq, aw16, lg);
  hipLaunchKernelGGL(bag_sum, dim3(NBAGS), dim3(192), 0, stream, x, lg, scope,
                     out, lt16);

  float* probs = out + (size_t)3 * NBAGS * DIM + (size_t)NBAGS * KTOT;
  hipLaunchKernelGGL(probs_mfma, dim3(NBAGS / 64), dim3(256), 0, stream, lt16,
                     rw16, bias, probs);
}